// Round 2
// baseline (2910.403 us; speedup 1.0000x reference)
//
#include <hip/hip_runtime.h>
#include <stdint.h>
#include <stddef.h>

// ScannedRNN: SEQ=512 BATCH=128 D_IN=512 H=512
// Fused design (no G buffer; ws ~3.3MB):
//   k_detect : resets dtype sniff (int32 vs byte) -> ws flag
//   k_starts : chunk starts snapped to resets (reset => h=0 => parallel restart points)
//   k_swz    : W_in/W_h f32 -> bf16 MFMA B-fragment order in ws (L2 resident, 3MB)
//   k_scan   : 256 WGs x 64 chunk-walker rows. Per step, per walker row:
//              gates = ins[ts] @ W_in + b_in  (A-frags straight from global f32, cvt to bf16)
//                    + h @ W_h               (A-frags from 64KB LDS bf16 tile)
//              z/r input+hidden fused in one accumulator; n_in / n_h kept separate.
//              h carried f32 through `outputs` (blend read = same-thread RAW;
//              refill read = cross-thread, guarded by __threadfence + volatile).
// BUGFIX vs round 1: all __shfl hoisted to uniform control flow (ds_bpermute
// pulls from exec-disabled lanes return undefined data -> garbage timesteps
// once walkers diverge). No more shfl under activity predication.

#define SEQ   512
#define BATCH 128
#define DIN   512
#define HD    512
#define G3    1536

typedef __attribute__((ext_vector_type(8))) short bf16x8;
typedef __attribute__((ext_vector_type(4))) float f32x4;

#define WS_FLAG_OFF   0
#define WS_STARTS_OFF 256
#define WS_SWZIN_OFF  131072
#define WS_SWZH_OFF   (131072 + 1572864)

__device__ __forceinline__ unsigned short f2bf(float x){
  union { float f; unsigned u; } v; v.f = x;
  return (unsigned short)((v.u + 0x7FFFu + ((v.u >> 16) & 1u)) >> 16);
}
__device__ __forceinline__ float bf2f(unsigned short u){
  union { unsigned u; float f; } v; v.u = ((unsigned)u) << 16; return v.f;
}
__device__ __forceinline__ int get_reset(const void* r, int flag, int idx){
  return flag ? (((const int*)r)[idx] != 0)
              : (((const unsigned char*)r)[idx] != 0);
}
// XOR-swizzled 16B-chunk address for the 64x512 bf16 A tile (row stride 1024B):
// breaks the power-of-2-stride bank conflict; residual 2-way is free (m136).
__device__ __forceinline__ int h_addr(int row, int kc){
  return row * 1024 + ((kc ^ (row & 7)) << 4);
}
__device__ __forceinline__ bf16x8 pack8(float4 a, float4 c){
  bf16x8 v;
  v[0]=(short)f2bf(a.x); v[1]=(short)f2bf(a.y); v[2]=(short)f2bf(a.z); v[3]=(short)f2bf(a.w);
  v[4]=(short)f2bf(c.x); v[5]=(short)f2bf(c.y); v[6]=(short)f2bf(c.z); v[7]=(short)f2bf(c.w);
  return v;
}

__global__ void k_detect(const int* resets, int* flag){
  __shared__ int bad;
  if (threadIdx.x == 0) bad = 0;
  __syncthreads();
  int ok = 1;
  for (int i = threadIdx.x; i < 4096; i += 256){
    int v = resets[i];
    if (v != 0 && v != 1) ok = 0;
  }
  if (!ok) atomicOr(&bad, 1);
  __syncthreads();
  if (threadIdx.x == 0) *flag = bad ? 0 : 1;
}

__global__ void k_starts(const void* resets, const int* flag, int* starts){
  int x = blockIdx.x * 256 + threadIdx.x;      // chunk id, 16384 total
  int b = x >> 7, c = x & 127;                 // 128 chunks per batch row, W=4
  int f = *flag;
  int t = 0;
  if (c != 0){
    t = c * 4;
    while (t < SEQ && !get_reset(resets, f, t * BATCH + b)) t++;
  }
  starts[x] = t;
}

__global__ void k_swz(const float* Win, const float* Wh,
                      unsigned short* swz_in, unsigned short* swz_h){
  int id = blockIdx.x * 256 + threadIdx.x;     // 2*96*16*64 = 196608
  int l  = id & 63; id >>= 6;
  int kt = id & 15; id >>= 4;
  int nt = id % 96; int which = id / 96;
  const float* W = which ? Wh : Win;
  unsigned short* o = which ? swz_h : swz_in;
  int kbase = kt * 32 + (l >> 4) * 8;
  int col   = nt * 16 + (l & 15);
  bf16x8 v;
#pragma unroll
  for (int j = 0; j < 8; ++j) v[j] = (short)f2bf(W[(size_t)(kbase + j) * G3 + col]);
  ((bf16x8*)o)[(size_t)(nt * 16 + kt) * 64 + l] = v;
}

__launch_bounds__(256, 1)
__global__ void k_scan(const void* resets, const int* flag, const int* starts,
                       const unsigned short* swz_in, const unsigned short* swz_h,
                       const float* b_in, const float* ins,
                       float* out_final, float* outputs){
  __shared__ unsigned short hS[64 * 512];      // 64KB bf16 h A-tile, swizzled
  const int tid = threadIdx.x, lane = tid & 63, w = tid >> 6;
  const int quad = lane >> 4, lm = lane & 15;
  const int g = blockIdx.x;
  const int b = g >> 1;
  const int f = *flag;
  const int chunk = g * 64 + lane;             // every lane = one walker row
  const int t_start = starts[chunk];
  const int t_end = ((chunk & 127) == 127) ? SEQ : starts[chunk + 1];
  int t_cur = t_start;

  for (int i = tid; i < 4096; i += 256){
    bf16x8 z;
#pragma unroll
    for (int j = 0; j < 8; ++j) z[j] = 0;
    *(bf16x8*)((char*)hS + h_addr(i >> 6, i & 63)) = z;
  }
  __syncthreads();

  for (int guard = 0; guard < SEQ + 8; ++guard){
    bool active = t_cur < t_end;
    unsigned long long bal_act = __ballot(active);
    if (bal_act == 0ull) break;
    bool rst = active && (t_cur == t_start || get_reset(resets, f, t_cur * BATCH + b));
    unsigned long long bal_rst = __ballot(rst);
    int t_next = active ? t_cur + 1 : t_cur;
    bool rstn = active && (t_next < t_end) && get_reset(resets, f, t_next * BATCH + b);
    unsigned long long bal_rstn = __ballot(rstn);

    // ---- uniform-control-flow shfl precompute (BUGFIX) ----
    int ts_q[16];
#pragma unroll
    for (int mt = 0; mt < 4; ++mt)
#pragma unroll
      for (int r = 0; r < 4; ++r)
        ts_q[mt * 4 + r] = __shfl(t_cur, mt * 16 + quad * 4 + r, 64);
    int ts_a[4];
#pragma unroll
    for (int mt = 0; mt < 4; ++mt){
      int t = __shfl(t_cur, mt * 16 + lm, 64);
      ts_a[mt] = (t < SEQ) ? t : 0;            // finished walkers: safe dummy row
    }
    int ts_r = __shfl(t_cur, tid >> 2, 64);    // for refill (s = tid>>2)

    for (int itz = 0; itz < 4; ++itz){
      int z0 = w * 8 + itz * 2;
      // acc comp: [0]=z(in+h fused) [1]=r(fused) [2]=n_in [3]=n_h
      f32x4 acc[4][2][4];
#pragma unroll
      for (int mt = 0; mt < 4; ++mt)
#pragma unroll
        for (int zi = 0; zi < 2; ++zi)
#pragma unroll
          for (int p = 0; p < 4; ++p) acc[mt][zi][p] = (f32x4){0.f,0.f,0.f,0.f};

      for (int kt = 0; kt < 16; ++kt){
        bf16x8 ah[4], ai[4];
#pragma unroll
        for (int mt = 0; mt < 4; ++mt)
          ah[mt] = *(bf16x8*)((char*)hS + h_addr(mt * 16 + lm, kt * 4 + quad));
#pragma unroll
        for (int mt = 0; mt < 4; ++mt){
          const float* p = ins + ((size_t)ts_a[mt] * BATCH + b) * DIN + kt * 32 + quad * 8;
          float4 x = ((const float4*)p)[0];
          float4 y = ((const float4*)p)[1];
          ai[mt] = pack8(x, y);
        }
#pragma unroll
        for (int zi = 0; zi < 2; ++zi){
          int zt = z0 + zi;
          bf16x8 Bi0 = ((const bf16x8*)swz_in)[((size_t)(zt)      * 16 + kt) * 64 + lane];
          bf16x8 Bh0 = ((const bf16x8*)swz_h )[((size_t)(zt)      * 16 + kt) * 64 + lane];
          bf16x8 Bi1 = ((const bf16x8*)swz_in)[((size_t)(32 + zt) * 16 + kt) * 64 + lane];
          bf16x8 Bh1 = ((const bf16x8*)swz_h )[((size_t)(32 + zt) * 16 + kt) * 64 + lane];
          bf16x8 Bi2 = ((const bf16x8*)swz_in)[((size_t)(64 + zt) * 16 + kt) * 64 + lane];
          bf16x8 Bh2 = ((const bf16x8*)swz_h )[((size_t)(64 + zt) * 16 + kt) * 64 + lane];
#pragma unroll
          for (int mt = 0; mt < 4; ++mt){
            acc[mt][zi][0] = __builtin_amdgcn_mfma_f32_16x16x32_bf16(ah[mt], Bh0, acc[mt][zi][0], 0,0,0);
            acc[mt][zi][0] = __builtin_amdgcn_mfma_f32_16x16x32_bf16(ai[mt], Bi0, acc[mt][zi][0], 0,0,0);
            acc[mt][zi][1] = __builtin_amdgcn_mfma_f32_16x16x32_bf16(ah[mt], Bh1, acc[mt][zi][1], 0,0,0);
            acc[mt][zi][1] = __builtin_amdgcn_mfma_f32_16x16x32_bf16(ai[mt], Bi1, acc[mt][zi][1], 0,0,0);
            acc[mt][zi][2] = __builtin_amdgcn_mfma_f32_16x16x32_bf16(ai[mt], Bi2, acc[mt][zi][2], 0,0,0);
            acc[mt][zi][3] = __builtin_amdgcn_mfma_f32_16x16x32_bf16(ah[mt], Bh2, acc[mt][zi][3], 0,0,0);
          }
        }
      }

      // gate math + output writes (C layout: row = quad*4+reg, col = lane&15)
#pragma unroll
      for (int zi = 0; zi < 2; ++zi){
        int col = (z0 + zi) * 16 + lm;
        float bz = b_in[col];
        float br = b_in[col + 512];
        float bn = b_in[col + 1024];
#pragma unroll
        for (int mt = 0; mt < 4; ++mt){
#pragma unroll
          for (int r = 0; r < 4; ++r){
            int s = mt * 16 + quad * 4 + r;
            if (!((bal_act >> s) & 1ull)) continue;
            int ts = ts_q[mt * 4 + r];
            bool rs = (bal_rst >> s) & 1ull;
            float zg = 1.f / (1.f + __expf(-(acc[mt][zi][0][r] + bz)));
            float rg = 1.f / (1.f + __expf(-(acc[mt][zi][1][r] + br)));
            float pre = acc[mt][zi][2][r] + bn + rg * acc[mt][zi][3][r];
            float e = __expf(-2.f * fabsf(pre));
            float nn = copysignf((1.f - e) / (1.f + e), pre);
            float hp = rs ? 0.f : outputs[((size_t)(ts - 1) * BATCH + b) * HD + col];
            float hn = (1.f - zg) * nn + zg * hp;
            outputs[((size_t)ts * BATCH + b) * HD + col] = hn;
            if (ts == SEQ - 1) out_final[(size_t)b * HD + col] = hn;
          }
        }
      }
    }

    __threadfence();
    __syncthreads();
    // refill hS (bf16) from just-written f32 outputs; pre-zero rows resetting next step
    {
      int s = tid >> 2, part = tid & 3;
      if ((bal_act >> s) & 1ull){
        bool rz = (bal_rstn >> s) & 1ull;
        const volatile float* src = outputs + ((size_t)ts_r * BATCH + b) * HD + part * 128;
#pragma unroll
        for (int i = 0; i < 16; ++i){
          int kc = part * 16 + i;
          bf16x8 v;
          if (rz){
#pragma unroll
            for (int j = 0; j < 8; ++j) v[j] = 0;
          } else {
#pragma unroll
            for (int j = 0; j < 8; ++j) v[j] = (short)f2bf(src[i * 8 + j]);
          }
          *(bf16x8*)((char*)hS + h_addr(s, kc)) = v;
        }
      }
    }
    t_cur = t_next;
    __syncthreads();
  }
}

extern "C" void kernel_launch(void* const* d_in, const int* in_sizes, int n_in,
                              void* d_out, int out_size, void* d_ws, size_t ws_size,
                              hipStream_t stream) {
  const float* ins   = (const float*)d_in[1];
  const void*  rsts  = d_in[2];
  const float* W_in  = (const float*)d_in[3];
  const float* b_in  = (const float*)d_in[4];
  const float* W_h   = (const float*)d_in[5];

  char* ws = (char*)d_ws;
  int* flag            = (int*)(ws + WS_FLAG_OFF);
  int* starts          = (int*)(ws + WS_STARTS_OFF);
  unsigned short* swzi = (unsigned short*)(ws + WS_SWZIN_OFF);
  unsigned short* swzh = (unsigned short*)(ws + WS_SWZH_OFF);

  float* out_final = (float*)d_out;                  // (128,512)
  float* outputs   = (float*)d_out + BATCH * HD;     // (512,128,512)

  k_detect<<<1, 256, 0, stream>>>((const int*)rsts, flag);
  k_starts<<<64, 256, 0, stream>>>(rsts, flag, starts);
  k_swz<<<768, 256, 0, stream>>>(W_in, W_h, swzi, swzh);
  k_scan<<<256, 256, 0, stream>>>(rsts, flag, starts, swzi, swzh, b_in, ins,
                                  out_final, outputs);
}

// Round 3
// 2292.234 us; speedup vs baseline: 1.2697x; 1.2697x over previous
//
#include <hip/hip_runtime.h>
#include <stdint.h>
#include <stddef.h>

// ScannedRNN: SEQ=512 BATCH=128 D_IN=512 H=512
// Round 3: hoist input-gate GEMM out of the serial loop.
//   k_detect : resets dtype sniff (int32 vs byte) -> ws flag
//   k_starts : chunk starts snapped to resets (reset => h=0 => parallel restart)
//   k_swz    : W_in/W_h f32 -> bf16 MFMA B-fragment order in ws (3MB, L2 resident)
//   k_gates  : G = ins@W_in + b_in, bf16 [65536 x 1536] in ws (201MB) - parallel GEMM
//   k_scan   : 256 WGs x 64 walker rows; per step only h@W_h (MFMA) + G epilogue
//              reads. Per-WG-step L2 traffic drops 5MB -> 1.7MB vs round 2.
// Layout patterns (A-frag, B-frag swizzle, C-layout, refill/fence) are
// exactly the round-2-validated ones.

#define SEQ   512
#define BATCH 128
#define DIN   512
#define HD    512
#define G3    1536

typedef __attribute__((ext_vector_type(8))) short bf16x8;
typedef __attribute__((ext_vector_type(4))) float f32x4;

#define WS_FLAG_OFF   0
#define WS_STARTS_OFF 256
#define WS_SWZIN_OFF  131072
#define WS_SWZH_OFF   (131072 + 1572864)
#define WS_G_OFF      4194304          // 65536*1536*2B = 201.3MB

__device__ __forceinline__ unsigned short f2bf(float x){
  union { float f; unsigned u; } v; v.f = x;
  return (unsigned short)((v.u + 0x7FFFu + ((v.u >> 16) & 1u)) >> 16);
}
__device__ __forceinline__ float bf2f(unsigned short u){
  union { unsigned u; float f; } v; v.u = ((unsigned)u) << 16; return v.f;
}
__device__ __forceinline__ int get_reset(const void* r, int flag, int idx){
  return flag ? (((const int*)r)[idx] != 0)
              : (((const unsigned char*)r)[idx] != 0);
}
// XOR-swizzled 16B-chunk address for 64x512 bf16 A tile (row stride 1024B).
__device__ __forceinline__ int h_addr(int row, int kc){
  return row * 1024 + ((kc ^ (row & 7)) << 4);
}
__device__ __forceinline__ bf16x8 pack8(float4 a, float4 c){
  bf16x8 v;
  v[0]=(short)f2bf(a.x); v[1]=(short)f2bf(a.y); v[2]=(short)f2bf(a.z); v[3]=(short)f2bf(a.w);
  v[4]=(short)f2bf(c.x); v[5]=(short)f2bf(c.y); v[6]=(short)f2bf(c.z); v[7]=(short)f2bf(c.w);
  return v;
}

__global__ void k_detect(const int* resets, int* flag){
  __shared__ int bad;
  if (threadIdx.x == 0) bad = 0;
  __syncthreads();
  int ok = 1;
  for (int i = threadIdx.x; i < 4096; i += 256){
    int v = resets[i];
    if (v != 0 && v != 1) ok = 0;
  }
  if (!ok) atomicOr(&bad, 1);
  __syncthreads();
  if (threadIdx.x == 0) *flag = bad ? 0 : 1;
}

__global__ void k_starts(const void* resets, const int* flag, int* starts){
  int x = blockIdx.x * 256 + threadIdx.x;      // chunk id, 16384 total
  int b = x >> 7, c = x & 127;                 // 128 chunks per batch row, W=4
  int f = *flag;
  int t = 0;
  if (c != 0){
    t = c * 4;
    while (t < SEQ && !get_reset(resets, f, t * BATCH + b)) t++;
  }
  starts[x] = t;
}

__global__ void k_swz(const float* Win, const float* Wh,
                      unsigned short* swz_in, unsigned short* swz_h){
  int id = blockIdx.x * 256 + threadIdx.x;     // 2*96*16*64 = 196608
  int l  = id & 63; id >>= 6;
  int kt = id & 15; id >>= 4;
  int nt = id % 96; int which = id / 96;
  const float* W = which ? Wh : Win;
  unsigned short* o = which ? swz_h : swz_in;
  int kbase = kt * 32 + (l >> 4) * 8;
  int col   = nt * 16 + (l & 15);
  bf16x8 v;
#pragma unroll
  for (int j = 0; j < 8; ++j) v[j] = (short)f2bf(W[(size_t)(kbase + j) * G3 + col]);
  ((bf16x8*)o)[(size_t)(nt * 16 + kt) * 64 + l] = v;
}

__launch_bounds__(256, 1)
__global__ void k_gates(const float* ins, const float* b_in,
                        const unsigned short* swzW, unsigned short* G){
  __shared__ unsigned short hA[64 * 512];      // 64KB, swizzled
  const int tid = threadIdx.x;
  const int row0 = blockIdx.x * 64;
#pragma unroll
  for (int i = 0; i < 16; ++i){
    int cid = i * 256 + tid;                   // 4096 16B chunks
    int r = cid >> 6, kc = cid & 63;
    const float* src = ins + (size_t)(row0 + r) * DIN + kc * 8;
    float4 a = ((const float4*)src)[0];
    float4 c = ((const float4*)src)[1];
    *(bf16x8*)((char*)hA + h_addr(r, kc)) = pack8(a, c);
  }
  __syncthreads();
  const int lane = tid & 63, w = tid >> 6;
  const int quad = lane >> 4, lm = lane & 15;
  for (int itn = 0; itn < 4; ++itn){           // wave covers nt [24w, 24w+24)
    int ntb = w * 24 + itn * 6;
    f32x4 acc[4][6];
#pragma unroll
    for (int mt = 0; mt < 4; ++mt)
#pragma unroll
      for (int n = 0; n < 6; ++n) acc[mt][n] = (f32x4){0.f,0.f,0.f,0.f};
    for (int kt = 0; kt < 16; ++kt){
      bf16x8 a[4];
#pragma unroll
      for (int mt = 0; mt < 4; ++mt)
        a[mt] = *(bf16x8*)((char*)hA + h_addr(mt * 16 + lm, kt * 4 + quad));
#pragma unroll
      for (int n = 0; n < 6; ++n){
        bf16x8 bfr = ((const bf16x8*)swzW)[(size_t)((ntb + n) * 16 + kt) * 64 + lane];
#pragma unroll
        for (int mt = 0; mt < 4; ++mt)
          acc[mt][n] = __builtin_amdgcn_mfma_f32_16x16x32_bf16(a[mt], bfr, acc[mt][n], 0, 0, 0);
      }
    }
#pragma unroll
    for (int n = 0; n < 6; ++n){
      int col = (ntb + n) * 16 + lm;
      float bias = b_in[col];
#pragma unroll
      for (int mt = 0; mt < 4; ++mt){
        int gr = row0 + mt * 16 + quad * 4;
#pragma unroll
        for (int r = 0; r < 4; ++r)
          G[(size_t)(gr + r) * G3 + col] = f2bf(acc[mt][n][r] + bias);
      }
    }
  }
}

__launch_bounds__(256, 1)
__global__ void k_scan(const void* resets, const int* flag, const int* starts,
                       const unsigned short* swz_h, const unsigned short* G,
                       float* out_final, float* outputs){
  __shared__ unsigned short hS[64 * 512];      // 64KB bf16 h A-tile, swizzled
  const int tid = threadIdx.x, lane = tid & 63, w = tid >> 6;
  const int quad = lane >> 4, lm = lane & 15;
  const int g = blockIdx.x;
  const int b = g >> 1;
  const int f = *flag;
  const int chunk = g * 64 + lane;             // every lane = one walker row
  const int t_start = starts[chunk];
  const int t_end = ((chunk & 127) == 127) ? SEQ : starts[chunk + 1];
  int t_cur = t_start;

  for (int i = tid; i < 4096; i += 256){
    bf16x8 z;
#pragma unroll
    for (int j = 0; j < 8; ++j) z[j] = 0;
    *(bf16x8*)((char*)hS + h_addr(i >> 6, i & 63)) = z;
  }
  __syncthreads();

  for (int guard = 0; guard < SEQ + 8; ++guard){
    bool active = t_cur < t_end;
    unsigned long long bal_act = __ballot(active);
    if (bal_act == 0ull) break;
    bool rst = active && (t_cur == t_start || get_reset(resets, f, t_cur * BATCH + b));
    unsigned long long bal_rst = __ballot(rst);
    int t_next = active ? t_cur + 1 : t_cur;
    bool rstn = active && (t_next < t_end) && get_reset(resets, f, t_next * BATCH + b);
    unsigned long long bal_rstn = __ballot(rstn);

    // uniform-control-flow shfl precompute (exec-mask rule)
    int ts_q[16];
#pragma unroll
    for (int mt = 0; mt < 4; ++mt)
#pragma unroll
      for (int r = 0; r < 4; ++r)
        ts_q[mt * 4 + r] = __shfl(t_cur, mt * 16 + quad * 4 + r, 64);
    int ts_r = __shfl(t_cur, tid >> 2, 64);    // for refill (s = tid>>2)

    for (int itz = 0; itz < 4; ++itz){
      int z0 = w * 8 + itz * 2;
      // acc comp: [0]=z_h [1]=r_h [2]=n_h
      f32x4 acc[4][2][3];
#pragma unroll
      for (int mt = 0; mt < 4; ++mt)
#pragma unroll
        for (int zi = 0; zi < 2; ++zi)
#pragma unroll
          for (int p = 0; p < 3; ++p) acc[mt][zi][p] = (f32x4){0.f,0.f,0.f,0.f};

      for (int kt = 0; kt < 16; ++kt){
        bf16x8 ah[4];
#pragma unroll
        for (int mt = 0; mt < 4; ++mt)
          ah[mt] = *(bf16x8*)((char*)hS + h_addr(mt * 16 + lm, kt * 4 + quad));
#pragma unroll
        for (int zi = 0; zi < 2; ++zi){
          int zt = z0 + zi;
          bf16x8 B0 = ((const bf16x8*)swz_h)[((size_t)(zt)      * 16 + kt) * 64 + lane];
          bf16x8 B1 = ((const bf16x8*)swz_h)[((size_t)(32 + zt) * 16 + kt) * 64 + lane];
          bf16x8 B2 = ((const bf16x8*)swz_h)[((size_t)(64 + zt) * 16 + kt) * 64 + lane];
#pragma unroll
          for (int mt = 0; mt < 4; ++mt){
            acc[mt][zi][0] = __builtin_amdgcn_mfma_f32_16x16x32_bf16(ah[mt], B0, acc[mt][zi][0], 0,0,0);
            acc[mt][zi][1] = __builtin_amdgcn_mfma_f32_16x16x32_bf16(ah[mt], B1, acc[mt][zi][1], 0,0,0);
            acc[mt][zi][2] = __builtin_amdgcn_mfma_f32_16x16x32_bf16(ah[mt], B2, acc[mt][zi][2], 0,0,0);
          }
        }
      }

      // gate math + output writes (C layout: row = quad*4+reg, col = lane&15)
#pragma unroll
      for (int zi = 0; zi < 2; ++zi){
        int col = (z0 + zi) * 16 + lm;
#pragma unroll
        for (int mt = 0; mt < 4; ++mt){
#pragma unroll
          for (int r = 0; r < 4; ++r){
            int s = mt * 16 + quad * 4 + r;
            if (!((bal_act >> s) & 1ull)) continue;
            int ts = ts_q[mt * 4 + r];
            bool rs = (bal_rst >> s) & 1ull;
            size_t gb = ((size_t)ts * BATCH + b) * G3;
            float zg = 1.f / (1.f + __expf(-(bf2f(G[gb + col])        + acc[mt][zi][0][r])));
            float rg = 1.f / (1.f + __expf(-(bf2f(G[gb + 512 + col])  + acc[mt][zi][1][r])));
            float pre = bf2f(G[gb + 1024 + col]) + rg * acc[mt][zi][2][r];
            float e = __expf(-2.f * fabsf(pre));
            float nn = copysignf((1.f - e) / (1.f + e), pre);
            float hp = rs ? 0.f : outputs[((size_t)(ts - 1) * BATCH + b) * HD + col];
            float hn = (1.f - zg) * nn + zg * hp;
            outputs[((size_t)ts * BATCH + b) * HD + col] = hn;
            if (ts == SEQ - 1) out_final[(size_t)b * HD + col] = hn;
          }
        }
      }
    }

    __threadfence();
    __syncthreads();
    // refill hS (bf16) from just-written f32 outputs; pre-zero rows resetting next
    {
      int s = tid >> 2, part = tid & 3;
      if ((bal_act >> s) & 1ull){
        bool rz = (bal_rstn >> s) & 1ull;
        const volatile float* src = outputs + ((size_t)ts_r * BATCH + b) * HD + part * 128;
#pragma unroll
        for (int i = 0; i < 16; ++i){
          int kc = part * 16 + i;
          bf16x8 v;
          if (rz){
#pragma unroll
            for (int j = 0; j < 8; ++j) v[j] = 0;
          } else {
#pragma unroll
            for (int j = 0; j < 8; ++j) v[j] = (short)f2bf(src[i * 8 + j]);
          }
          *(bf16x8*)((char*)hS + h_addr(s, kc)) = v;
        }
      }
    }
    t_cur = t_next;
    __syncthreads();
  }
}

extern "C" void kernel_launch(void* const* d_in, const int* in_sizes, int n_in,
                              void* d_out, int out_size, void* d_ws, size_t ws_size,
                              hipStream_t stream) {
  const float* ins   = (const float*)d_in[1];
  const void*  rsts  = d_in[2];
  const float* W_in  = (const float*)d_in[3];
  const float* b_in  = (const float*)d_in[4];
  const float* W_h   = (const float*)d_in[5];

  char* ws = (char*)d_ws;
  int* flag            = (int*)(ws + WS_FLAG_OFF);
  int* starts          = (int*)(ws + WS_STARTS_OFF);
  unsigned short* swzi = (unsigned short*)(ws + WS_SWZIN_OFF);
  unsigned short* swzh = (unsigned short*)(ws + WS_SWZH_OFF);
  unsigned short* G    = (unsigned short*)(ws + WS_G_OFF);

  float* out_final = (float*)d_out;                  // (128,512)
  float* outputs   = (float*)d_out + BATCH * HD;     // (512,128,512)

  k_detect<<<1, 256, 0, stream>>>((const int*)rsts, flag);
  k_starts<<<64, 256, 0, stream>>>(rsts, flag, starts);
  k_swz<<<768, 256, 0, stream>>>(W_in, W_h, swzi, swzh);
  k_gates<<<1024, 256, 0, stream>>>(ins, b_in, swzi, G);
  k_scan<<<256, 256, 0, stream>>>(rsts, flag, starts, swzh, G, out_final, outputs);
}